// Round 9
// baseline (485.390 us; speedup 1.0000x reference)
//
#include <hip/hip_runtime.h>
#include <math.h>
#include <stdint.h>

#define B_ 8
#define S_ 2048
#define E_ 1024
#define D_ 64
#define PWLDU 36   // per-wave P-exchange row stride in u32 (144 B, 16B-aligned)

typedef __attribute__((ext_vector_type(8))) short bf16x8;
typedef __attribute__((ext_vector_type(4))) float f32x4;
typedef __attribute__((ext_vector_type(4))) unsigned u32x4;

static __device__ __forceinline__ unsigned short f2bf(float f) {
    union { float f; unsigned u; } v; v.f = f;
    unsigned r = v.u + 0x7FFFu + ((v.u >> 16) & 1u);   // RNE
    return (unsigned short)(r >> 16);
}

// packed bf16 pair via HW cvt (RNE): D[15:0]=bf16(lo), D[31:16]=bf16(hi)
static __device__ __forceinline__ unsigned cvtpk(float lo, float hi) {
    unsigned r;
    asm("v_cvt_pk_bf16_f32 %0, %1, %2" : "=v"(r) : "v"(lo), "v"(hi));
    return r;
}

// ---------------------------------------------------------------------------
// K0: convert W (fp32 [3][64][1024]) -> bf16, same layout (L2-resident, 384 KB).
// ---------------------------------------------------------------------------
__global__ __launch_bounds__(256) void wconv_kernel(
    const float* __restrict__ Wq, const float* __restrict__ Wk,
    const float* __restrict__ Wv, unsigned short* __restrict__ Wb)
{
    const int which = blockIdx.x >> 6;                 // 64 blocks per matrix
    const float* W = (which == 0) ? Wq : (which == 1) ? Wk : Wv;
    const int i = ((blockIdx.x & 63) * 256 + threadIdx.x) * 4;
    float4 v = *(const float4*)(W + i);
    union { unsigned u32[2]; ushort4 s; } o;
    o.u32[0] = cvtpk(v.x, v.y);
    o.u32[1] = cvtpk(v.z, v.w);
    *(ushort4*)(Wb + (size_t)which * 65536 + i) = o.s;
}

// ---------------------------------------------------------------------------
// K1: projections, NO LDS / NO barriers (unchanged from measured version).
// ---------------------------------------------------------------------------
__global__ __launch_bounds__(256) void proj_kernel(
    const float* __restrict__ Xq, const float* __restrict__ Xk,
    const float* __restrict__ Xv, const unsigned short* __restrict__ Wb,
    unsigned short* __restrict__ Qb, unsigned short* __restrict__ Kb,
    unsigned short* __restrict__ VTb)
{
    const int which = blockIdx.y;
    const float* __restrict__ X = (which == 0) ? Xq : (which == 1) ? Xk : Xv;
    const unsigned short* __restrict__ W = Wb + (size_t)which * 65536;

    const int tid  = threadIdx.x;
    const int lane = tid & 63;
    const int wv   = tid >> 6;
    const int quad = lane >> 4;
    const int l15  = lane & 15;
    const int m    = blockIdx.x * 64 + wv * 16 + l15;   // A-frag row for this lane

    f32x4 acc[4];
    #pragma unroll
    for (int i = 0; i < 4; i++) { f32x4 z = {0.f, 0.f, 0.f, 0.f}; acc[i] = z; }

    const float* __restrict__ xrow = X + (size_t)m * E_;

    #pragma unroll 2
    for (int e0 = 0; e0 < E_; e0 += 64) {
        #pragma unroll
        for (int ks = 0; ks < 2; ks++) {
            const int k = e0 + ks * 32 + quad * 8;
            f32x4 a0 = __builtin_nontemporal_load((const f32x4*)(xrow + k));
            f32x4 a1 = __builtin_nontemporal_load((const f32x4*)(xrow + k + 4));
            union { unsigned u32[4]; bf16x8 v; } af;
            af.u32[0] = cvtpk(a0[0], a0[1]);
            af.u32[1] = cvtpk(a0[2], a0[3]);
            af.u32[2] = cvtpk(a1[0], a1[1]);
            af.u32[3] = cvtpk(a1[2], a1[3]);
            #pragma unroll
            for (int nt = 0; nt < 4; nt++) {
                bf16x8 bf = *(const bf16x8*)(W + (size_t)(16 * nt + l15) * E_ + k);
                acc[nt] = __builtin_amdgcn_mfma_f32_16x16x32_bf16(af.v, bf, acc[nt], 0, 0, 0);
            }
        }
    }

    if (which < 2) {
        unsigned short* O = (which == 0) ? Qb : Kb;
        #pragma unroll
        for (int nt = 0; nt < 4; nt++)
            #pragma unroll
            for (int reg = 0; reg < 4; reg++) {
                int mg = blockIdx.x * 64 + wv * 16 + quad * 4 + reg;
                int d  = 16 * nt + l15;
                O[(size_t)mg * D_ + d] = f2bf(acc[nt][reg]);
            }
    } else {
        #pragma unroll
        for (int nt = 0; nt < 4; nt++)
            #pragma unroll
            for (int reg = 0; reg < 4; reg++) {
                int mg = blockIdx.x * 64 + wv * 16 + quad * 4 + reg;
                int b  = mg >> 11, sl = mg & 2047;
                int d  = 16 * nt + l15;
                VTb[((size_t)b * D_ + d) * S_ + sl] = f2bf(acc[nt][reg]);
            }
    }
}

// ---------------------------------------------------------------------------
// K2: fused attention, occupancy-focused revision (compile-fixed R6 design).
// Grid 1024: each block owns 16 q-rows of one batch. 8 waves = 8 t-eighths
// (256 t each); waves share NOTHING inside loops (zero in-loop barriers).
// Swapped QK^T mfma(K_n, Q): lane(quad,l15) holds P[t=t0+16n+quad*4+reg][s=l15].
// LDS ~27 KB; O-partials via LDS atomicAdd. __launch_bounds__(512,8) pins
// VGPR<=64. Target: 4 blocks/CU x 8 waves = 32 waves/CU (was 16).
// ---------------------------------------------------------------------------
__global__ __launch_bounds__(512, 8) void attn_kernel(
    const unsigned short* __restrict__ Qb, const unsigned short* __restrict__ Kb,
    const unsigned short* __restrict__ VTb, const unsigned char* __restrict__ mask,
    float* __restrict__ Sc, float* __restrict__ Att)
{
    __shared__ unsigned short Mb16[32 * 16 * 4];     // 4 KB  bit-packed mask [it][r][4 u16]
    __shared__ unsigned Pw[8][16 * PWLDU];           // 18 KB per-wave P exchange
    __shared__ float ObA[16 * 64];                   // 4 KB  O accumulator (atomic)
    __shared__ float Sums[8 * 16];
    __shared__ float Inv[16];

    const int tid  = threadIdx.x;
    const int lane = tid & 63;
    const int wv   = tid >> 6;            // 0..7 = t-eighth
    const int quad = lane >> 4, l15 = lane & 15;
    const int b  = blockIdx.x & 7;        // batch -> XCD affinity
    const int sB = (blockIdx.x >> 3) * 16;

    // ---- prologue: zero ObA; pack ALL mask bits (32 tiles x 16 rows x 64 c) ----
    ObA[tid] = 0.f;
    ObA[tid + 512] = 0.f;
    {
        const int r  = tid >> 5;          // 0..15
        const int it = tid & 31;          // 0..31
        const unsigned char* mrowp = mask + ((size_t)(b * S_ + sB + r)) * S_ + it * 64;
        #pragma unroll
        for (int c16 = 0; c16 < 4; c16++) {
            u32x4 u = __builtin_nontemporal_load((const u32x4*)(mrowp + c16 * 16));
            unsigned n0 = (u[0] | (u[0] >> 7) | (u[0] >> 14) | (u[0] >> 21)) & 0xFu;
            unsigned n1 = (u[1] | (u[1] >> 7) | (u[1] >> 14) | (u[1] >> 21)) & 0xFu;
            unsigned n2 = (u[2] | (u[2] >> 7) | (u[2] >> 14) | (u[2] >> 21)) & 0xFu;
            unsigned n3 = (u[3] | (u[3] >> 7) | (u[3] >> 14) | (u[3] >> 21)) & 0xFu;
            Mb16[(it * 16 + r) * 4 + c16] =
                (unsigned short)(n0 | (n1 << 4) | (n2 << 8) | (n3 << 12));
        }
    }
    const unsigned char* __restrict__ MbB = (const unsigned char*)Mb16;

    // Q B-frags (swapped QK: Q is the B operand; B-frag row = l15 = s)
    const unsigned short* __restrict__ qrow =
        Qb + ((size_t)(b * S_ + sB + l15)) * D_;
    const bf16x8 aq0 = *(const bf16x8*)(qrow + quad * 8);
    const bf16x8 aq1 = *(const bf16x8*)(qrow + 32 + quad * 8);

    const size_t kbase = (size_t)b * S_ * D_;
    const int tq0 = wv * 256;             // this wave's t-range start
    const int msh = (quad & 1) * 4;

    __syncthreads();   // Mb + ObA ready (barrier #1)

    // ---------------- pass A: sum of exp(logit), no barriers ----------------
    float sum_ = 0.f;
    #pragma unroll 2
    for (int itr = 0; itr < 4; itr++) {
        const int t0  = tq0 + itr * 64;
        const int itg = t0 >> 6;
        f32x4 a2[4];
        #pragma unroll
        for (int n = 0; n < 4; n++) {
            const unsigned short* kr = Kb + kbase + (size_t)(t0 + 16 * n + l15) * D_;
            bf16x8 k0 = *(const bf16x8*)(kr + quad * 8);
            bf16x8 k1 = *(const bf16x8*)(kr + 32 + quad * 8);
            f32x4 z = {0.f, 0.f, 0.f, 0.f};
            z = __builtin_amdgcn_mfma_f32_16x16x32_bf16(k0, aq0, z, 0, 0, 0);
            a2[n] = __builtin_amdgcn_mfma_f32_16x16x32_bf16(k1, aq1, z, 0, 0, 0);
        }
        #pragma unroll
        for (int n = 0; n < 4; n++) {
            unsigned mb = MbB[(itg * 16 + l15) * 8 + 2 * n + (quad >> 1)];
            #pragma unroll
            for (int reg = 0; reg < 4; reg++) {
                int bit = (mb >> (msh + reg)) & 1;
                sum_ += bit ? 0.f : __expf(a2[n][reg] * 0.125f);
            }
        }
    }
    // per-row partial over this wave's 256 t: reduce across the 4 quads
    sum_ += __shfl_xor(sum_, 16);
    sum_ += __shfl_xor(sum_, 32);
    if (lane < 16) Sums[wv * 16 + lane] = sum_;
    __syncthreads();   // barrier #2
    if (tid < 16) {
        float s = 0.f;
        #pragma unroll
        for (int w = 0; w < 8; w++) s += Sums[w * 16 + tid];
        Inv[tid] = 1.0f / s;
    }
    __syncthreads();
    const float inv_s = Inv[l15];         // loop-invariant per lane

    // ---------------- pass B: probs + PV, no barriers ----------------
    f32x4 o[4];
    #pragma unroll
    for (int i = 0; i < 4; i++) { f32x4 z = {0.f, 0.f, 0.f, 0.f}; o[i] = z; }

    #pragma unroll 1
    for (int itr = 0; itr < 4; itr++) {
        const int t0  = tq0 + itr * 64;
        const int itg = t0 >> 6;
        // V B-frags for PV (issued early; consumed at the end of the iter)
        bf16x8 vf[4][2];
        #pragma unroll
        for (int dblk = 0; dblk < 4; dblk++) {
            const unsigned short* vr = VTb + ((size_t)(b * D_ + 16 * dblk + l15)) * S_ + t0;
            vf[dblk][0] = *(const bf16x8*)(vr + quad * 8);
            vf[dblk][1] = *(const bf16x8*)(vr + 32 + quad * 8);
        }
        f32x4 a2[4];
        #pragma unroll
        for (int n = 0; n < 4; n++) {
            const unsigned short* kr = Kb + kbase + (size_t)(t0 + 16 * n + l15) * D_;
            bf16x8 k0 = *(const bf16x8*)(kr + quad * 8);
            bf16x8 k1 = *(const bf16x8*)(kr + 32 + quad * 8);
            f32x4 z = {0.f, 0.f, 0.f, 0.f};
            z = __builtin_amdgcn_mfma_f32_16x16x32_bf16(k0, aq0, z, 0, 0, 0);
            a2[n] = __builtin_amdgcn_mfma_f32_16x16x32_bf16(k1, aq1, z, 0, 0, 0);
        }
        #pragma unroll
        for (int n = 0; n < 4; n++) {
            unsigned mb = MbB[(itg * 16 + l15) * 8 + 2 * n + (quad >> 1)];
            f32x4 p;
            #pragma unroll
            for (int reg = 0; reg < 4; reg++) {
                int bit = (mb >> (msh + reg)) & 1;
                p[reg] = bit ? 0.f : __expf(a2[n][reg] * 0.125f) * inv_s;
            }
            // Sc: lane stores 4 consecutive t for its own row s -> 16 rows x 64B
            *(f32x4*)(Sc + ((size_t)(b * S_ + sB + l15)) * S_ + t0 + 16 * n + quad * 4) = p;
            // within-wave exchange staging: row l15 (=s), u32 cols 8n+2quad..+1
            unsigned pk0 = cvtpk(p[0], p[1]);
            unsigned pk1 = cvtpk(p[2], p[3]);
            Pw[wv][l15 * PWLDU + 8 * n + quad * 2]     = pk0;
            Pw[wv][l15 * PWLDU + 8 * n + quad * 2 + 1] = pk1;
        }
        asm volatile("" ::: "memory");    // keep ds_writes ordered before ds_reads
        // gather PV A-frags: row s=l15, t cols ks*32+quad*8..+7 (16B contiguous)
        bf16x8 pa0 = *(const bf16x8*)&Pw[wv][l15 * PWLDU + quad * 4];
        bf16x8 pa1 = *(const bf16x8*)&Pw[wv][l15 * PWLDU + 16 + quad * 4];
        #pragma unroll
        for (int dblk = 0; dblk < 4; dblk++) {
            o[dblk] = __builtin_amdgcn_mfma_f32_16x16x32_bf16(pa0, vf[dblk][0], o[dblk], 0, 0, 0);
            o[dblk] = __builtin_amdgcn_mfma_f32_16x16x32_bf16(pa1, vf[dblk][1], o[dblk], 0, 0, 0);
        }
    }

    // ---- accumulate O partials across the 8 t-eighth waves (LDS atomics) ----
    // PV C-layout: lane holds o[s=quad*4+reg][d=16*dblk+l15]
    #pragma unroll
    for (int dblk = 0; dblk < 4; dblk++)
        #pragma unroll
        for (int reg = 0; reg < 4; reg++)
            atomicAdd(&ObA[(quad * 4 + reg) * 64 + 16 * dblk + l15], o[dblk][reg]);
    __syncthreads();   // barrier #3
    if (tid < 256) {
        const int s  = tid >> 4;          // 0..15
        const int d0 = (tid & 15) * 4;
        *(f32x4*)(Att + ((size_t)(b * S_ + sB + s)) * D_ + d0) =
            *(const f32x4*)&ObA[s * 64 + d0];
    }
}

// ---------------------------------------------------------------------------
extern "C" void kernel_launch(void* const* d_in, const int* in_sizes, int n_in,
                              void* d_out, int out_size, void* d_ws, size_t ws_size,
                              hipStream_t stream)
{
    const float* q  = (const float*)d_in[0];
    const float* k  = (const float*)d_in[1];
    const float* v  = (const float*)d_in[2];
    const unsigned char* mask = (const unsigned char*)d_in[3];
    const float* wq = (const float*)d_in[4];
    const float* wk = (const float*)d_in[5];
    const float* wv = (const float*)d_in[6];

    float* out = (float*)d_out;
    float* Att = out;                                  // [B,S,D]
    float* Sc  = out + (size_t)B_ * S_ * D_;           // [B,S,S]

    // ws: Wb (384 KB) | Qb (2MB) | Kb (2MB) | VT (2MB)
    unsigned short* Wb = (unsigned short*)d_ws;
    unsigned short* Qb = Wb + (size_t)3 * 65536;
    unsigned short* Kb = Qb + (size_t)B_ * S_ * D_;
    unsigned short* VT = Kb + (size_t)B_ * S_ * D_;

    hipLaunchKernelGGL(wconv_kernel, dim3(192), dim3(256), 0, stream, wq, wk, wv, Wb);
    hipLaunchKernelGGL(proj_kernel, dim3(256, 3), dim3(256), 0, stream,
                       q, k, v, Wb, Qb, Kb, VT);
    hipLaunchKernelGGL(attn_kernel, dim3(1024), dim3(512), 0, stream,
                       Qb, Kb, VT, mask, Sc, Att);
}

// Round 13
// 450.771 us; speedup vs baseline: 1.0768x; 1.0768x over previous
//
#include <hip/hip_runtime.h>
#include <math.h>
#include <stdint.h>

#define B_ 8
#define S_ 2048
#define E_ 1024
#define D_ 64
#define PWLDU 36   // per-wave P-exchange row stride in u32 (144 B, 16B-aligned)

typedef __attribute__((ext_vector_type(8))) short bf16x8;
typedef __attribute__((ext_vector_type(4))) float f32x4;

static __device__ __forceinline__ unsigned short f2bf(float f) {
    union { float f; unsigned u; } v; v.f = f;
    unsigned r = v.u + 0x7FFFu + ((v.u >> 16) & 1u);   // RNE
    return (unsigned short)(r >> 16);
}

// packed bf16 pair via HW cvt (RNE): D[15:0]=bf16(lo), D[31:16]=bf16(hi)
static __device__ __forceinline__ unsigned cvtpk(float lo, float hi) {
    unsigned r;
    asm("v_cvt_pk_bf16_f32 %0, %1, %2" : "=v"(r) : "v"(lo), "v"(hi));
    return r;
}

// ---------------------------------------------------------------------------
// K0: convert W (fp32 [3][64][1024]) -> bf16, same layout (L2-resident, 384 KB).
// ---------------------------------------------------------------------------
__global__ __launch_bounds__(256) void wconv_kernel(
    const float* __restrict__ Wq, const float* __restrict__ Wk,
    const float* __restrict__ Wv, unsigned short* __restrict__ Wb)
{
    const int which = blockIdx.x >> 6;                 // 64 blocks per matrix
    const float* W = (which == 0) ? Wq : (which == 1) ? Wk : Wv;
    const int i = ((blockIdx.x & 63) * 256 + threadIdx.x) * 4;
    float4 v = *(const float4*)(W + i);
    union { unsigned u32[2]; ushort4 s; } o;
    o.u32[0] = cvtpk(v.x, v.y);
    o.u32[1] = cvtpk(v.z, v.w);
    *(ushort4*)(Wb + (size_t)which * 65536 + i) = o.s;
}

// ---------------------------------------------------------------------------
// K1: projections, NO LDS / NO barriers (unchanged from measured version).
// ---------------------------------------------------------------------------
__global__ __launch_bounds__(256) void proj_kernel(
    const float* __restrict__ Xq, const float* __restrict__ Xk,
    const float* __restrict__ Xv, const unsigned short* __restrict__ Wb,
    unsigned short* __restrict__ Qb, unsigned short* __restrict__ Kb,
    unsigned short* __restrict__ VTb)
{
    const int which = blockIdx.y;
    const float* __restrict__ X = (which == 0) ? Xq : (which == 1) ? Xk : Xv;
    const unsigned short* __restrict__ W = Wb + (size_t)which * 65536;

    const int tid  = threadIdx.x;
    const int lane = tid & 63;
    const int wv   = tid >> 6;
    const int quad = lane >> 4;
    const int l15  = lane & 15;
    const int m    = blockIdx.x * 64 + wv * 16 + l15;   // A-frag row for this lane

    f32x4 acc[4];
    #pragma unroll
    for (int i = 0; i < 4; i++) { f32x4 z = {0.f, 0.f, 0.f, 0.f}; acc[i] = z; }

    const float* __restrict__ xrow = X + (size_t)m * E_;

    #pragma unroll 2
    for (int e0 = 0; e0 < E_; e0 += 64) {
        #pragma unroll
        for (int ks = 0; ks < 2; ks++) {
            const int k = e0 + ks * 32 + quad * 8;
            f32x4 a0 = __builtin_nontemporal_load((const f32x4*)(xrow + k));
            f32x4 a1 = __builtin_nontemporal_load((const f32x4*)(xrow + k + 4));
            union { unsigned u32[4]; bf16x8 v; } af;
            af.u32[0] = cvtpk(a0[0], a0[1]);
            af.u32[1] = cvtpk(a0[2], a0[3]);
            af.u32[2] = cvtpk(a1[0], a1[1]);
            af.u32[3] = cvtpk(a1[2], a1[3]);
            #pragma unroll
            for (int nt = 0; nt < 4; nt++) {
                bf16x8 bf = *(const bf16x8*)(W + (size_t)(16 * nt + l15) * E_ + k);
                acc[nt] = __builtin_amdgcn_mfma_f32_16x16x32_bf16(af.v, bf, acc[nt], 0, 0, 0);
            }
        }
    }

    if (which < 2) {
        unsigned short* O = (which == 0) ? Qb : Kb;
        #pragma unroll
        for (int nt = 0; nt < 4; nt++)
            #pragma unroll
            for (int reg = 0; reg < 4; reg++) {
                int mg = blockIdx.x * 64 + wv * 16 + quad * 4 + reg;
                int d  = 16 * nt + l15;
                O[(size_t)mg * D_ + d] = f2bf(acc[nt][reg]);
            }
    } else {
        #pragma unroll
        for (int nt = 0; nt < 4; nt++)
            #pragma unroll
            for (int reg = 0; reg < 4; reg++) {
                int mg = blockIdx.x * 64 + wv * 16 + quad * 4 + reg;
                int b  = mg >> 11, sl = mg & 2047;
                int d  = 16 * nt + l15;
                VTb[((size_t)b * D_ + d) * S_ + sl] = f2bf(acc[nt][reg]);
            }
    }
}

// ---------------------------------------------------------------------------
// K2a: pass A only (pure-read kernel): row sums of exp(logit) -> Inv[B,S].
// Geometry/body identical to the measured R6 zero-barrier kernel's pass A:
// 512 blocks x 32 q-rows; 8 waves = 2 row-groups x 4 t-quarters.
// ---------------------------------------------------------------------------
__global__ __launch_bounds__(512) void sum_kernel(
    const unsigned short* __restrict__ Qb, const unsigned short* __restrict__ Kb,
    const unsigned char* __restrict__ mask, float* __restrict__ Invw)
{
    __shared__ unsigned char Mb[32 * 32 * 8];        // 8 KB bit-packed mask
    __shared__ float Sums[4 * 32];

    const int tid  = threadIdx.x;
    const int lane = tid & 63;
    const int wv   = tid >> 6;
    const int quad = lane >> 4, l15 = lane & 15;
    const int g    = wv >> 2;             // row-group
    const int qt   = wv & 3;              // t-quarter
    const int b  = blockIdx.x & 7;
    const int sB = (blockIdx.x >> 3) * 32;

    {
        const int ith = tid >> 8;
        const int r   = (tid & 255) >> 3;
        const int c8  = tid & 7;
        #pragma unroll 4
        for (int il = 0; il < 16; il++) {
            const int it = ith * 16 + il;
            unsigned long long u = __builtin_nontemporal_load(
                (const unsigned long long*)(mask +
                    ((size_t)(b * S_ + sB + r)) * S_ + it * 64 + c8 * 8));
            unsigned x = (unsigned)u, y = (unsigned)(u >> 32);
            unsigned n0 = (x | (x >> 7) | (x >> 14) | (x >> 21)) & 0xFu;
            unsigned n1 = (y | (y >> 7) | (y >> 14) | (y >> 21)) & 0xFu;
            Mb[(it * 32 + r) * 8 + c8] = (unsigned char)(n0 | (n1 << 4));
        }
    }

    const unsigned short* __restrict__ qrow =
        Qb + ((size_t)(b * S_ + sB + g * 16 + l15)) * D_;
    const bf16x8 aq0 = *(const bf16x8*)(qrow + quad * 8);
    const bf16x8 aq1 = *(const bf16x8*)(qrow + 32 + quad * 8);

    const size_t kbase = (size_t)b * S_ * D_;
    const int tq0 = qt * 512;
    const int mrow = g * 16 + l15;
    const int msh  = (quad & 1) * 4;

    __syncthreads();   // Mb ready

    float sum_ = 0.f;
    for (int itr = 0; itr < 8; itr++) {
        const int t0  = tq0 + itr * 64;
        const int itg = t0 >> 6;
        f32x4 a2[4];
        #pragma unroll
        for (int n = 0; n < 4; n++) {
            const unsigned short* kr = Kb + kbase + (size_t)(t0 + 16 * n + l15) * D_;
            bf16x8 k0 = *(const bf16x8*)(kr + quad * 8);
            bf16x8 k1 = *(const bf16x8*)(kr + 32 + quad * 8);
            f32x4 z = {0.f, 0.f, 0.f, 0.f};
            z = __builtin_amdgcn_mfma_f32_16x16x32_bf16(k0, aq0, z, 0, 0, 0);
            a2[n] = __builtin_amdgcn_mfma_f32_16x16x32_bf16(k1, aq1, z, 0, 0, 0);
        }
        #pragma unroll
        for (int n = 0; n < 4; n++) {
            unsigned mb = Mb[(itg * 32 + mrow) * 8 + 2 * n + (quad >> 1)];
            #pragma unroll
            for (int reg = 0; reg < 4; reg++) {
                int bit = (mb >> (msh + reg)) & 1;
                sum_ += bit ? 0.f : __expf(a2[n][reg] * 0.125f);
            }
        }
    }
    sum_ += __shfl_xor(sum_, 16);
    sum_ += __shfl_xor(sum_, 32);
    if (lane < 16) Sums[qt * 32 + g * 16 + lane] = sum_;
    __syncthreads();
    if (tid < 32) {
        float s = Sums[tid] + Sums[32 + tid] + Sums[64 + tid] + Sums[96 + tid];
        Invw[(size_t)b * S_ + sB + tid] = 1.0f / s;
    }
}

// ---------------------------------------------------------------------------
// K2b: pass B only: probs (Sc) + PV (Att), reading Inv from workspace.
// Body identical to the measured R6 zero-barrier kernel's pass B.
// ---------------------------------------------------------------------------
__global__ __launch_bounds__(512) void emit_kernel(
    const unsigned short* __restrict__ Qb, const unsigned short* __restrict__ Kb,
    const unsigned short* __restrict__ VTb, const unsigned char* __restrict__ mask,
    const float* __restrict__ Invw, float* __restrict__ Sc, float* __restrict__ Att)
{
    __shared__ unsigned char Mb[32 * 32 * 8];        // 8 KB
    __shared__ unsigned Pw[8][16 * PWLDU];           // 18 KB per-wave P exchange
    __shared__ float Ob[8][16][64];                  // 32 KB per-wave O partials

    const int tid  = threadIdx.x;
    const int lane = tid & 63;
    const int wv   = tid >> 6;
    const int quad = lane >> 4, l15 = lane & 15;
    const int g    = wv >> 2;
    const int qt   = wv & 3;
    const int b  = blockIdx.x & 7;
    const int sB = (blockIdx.x >> 3) * 32;

    {
        const int ith = tid >> 8;
        const int r   = (tid & 255) >> 3;
        const int c8  = tid & 7;
        #pragma unroll 4
        for (int il = 0; il < 16; il++) {
            const int it = ith * 16 + il;
            unsigned long long u = __builtin_nontemporal_load(
                (const unsigned long long*)(mask +
                    ((size_t)(b * S_ + sB + r)) * S_ + it * 64 + c8 * 8));
            unsigned x = (unsigned)u, y = (unsigned)(u >> 32);
            unsigned n0 = (x | (x >> 7) | (x >> 14) | (x >> 21)) & 0xFu;
            unsigned n1 = (y | (y >> 7) | (y >> 14) | (y >> 21)) & 0xFu;
            Mb[(it * 32 + r) * 8 + c8] = (unsigned char)(n0 | (n1 << 4));
        }
    }

    const unsigned short* __restrict__ qrow =
        Qb + ((size_t)(b * S_ + sB + g * 16 + l15)) * D_;
    const bf16x8 aq0 = *(const bf16x8*)(qrow + quad * 8);
    const bf16x8 aq1 = *(const bf16x8*)(qrow + 32 + quad * 8);

    const size_t kbase = (size_t)b * S_ * D_;
    const int tq0 = qt * 512;
    const int mrow = g * 16 + l15;
    const int msh  = (quad & 1) * 4;
    const float inv_s = Invw[(size_t)b * S_ + sB + mrow];

    __syncthreads();   // Mb ready

    f32x4 o[4];
    #pragma unroll
    for (int i = 0; i < 4; i++) { f32x4 z = {0.f, 0.f, 0.f, 0.f}; o[i] = z; }

    for (int itr = 0; itr < 8; itr++) {
        const int t0  = tq0 + itr * 64;
        const int itg = t0 >> 6;
        bf16x8 vf[4][2];
        #pragma unroll
        for (int dblk = 0; dblk < 4; dblk++) {
            const unsigned short* vr = VTb + ((size_t)(b * D_ + 16 * dblk + l15)) * S_ + t0;
            vf[dblk][0] = *(const bf16x8*)(vr + quad * 8);
            vf[dblk][1] = *(const bf16x8*)(vr + 32 + quad * 8);
        }
        f32x4 a2[4];
        #pragma unroll
        for (int n = 0; n < 4; n++) {
            const unsigned short* kr = Kb + kbase + (size_t)(t0 + 16 * n + l15) * D_;
            bf16x8 k0 = *(const bf16x8*)(kr + quad * 8);
            bf16x8 k1 = *(const bf16x8*)(kr + 32 + quad * 8);
            f32x4 z = {0.f, 0.f, 0.f, 0.f};
            z = __builtin_amdgcn_mfma_f32_16x16x32_bf16(k0, aq0, z, 0, 0, 0);
            a2[n] = __builtin_amdgcn_mfma_f32_16x16x32_bf16(k1, aq1, z, 0, 0, 0);
        }
        #pragma unroll
        for (int n = 0; n < 4; n++) {
            unsigned mb = Mb[(itg * 32 + mrow) * 8 + 2 * n + (quad >> 1)];
            f32x4 p;
            #pragma unroll
            for (int reg = 0; reg < 4; reg++) {
                int bit = (mb >> (msh + reg)) & 1;
                p[reg] = bit ? 0.f : __expf(a2[n][reg] * 0.125f) * inv_s;
            }
            *(f32x4*)(Sc + ((size_t)(b * S_ + sB + mrow)) * S_ + t0 + 16 * n + quad * 4) = p;
            unsigned pk0 = cvtpk(p[0], p[1]);
            unsigned pk1 = cvtpk(p[2], p[3]);
            Pw[wv][l15 * PWLDU + 8 * n + quad * 2]     = pk0;
            Pw[wv][l15 * PWLDU + 8 * n + quad * 2 + 1] = pk1;
        }
        asm volatile("" ::: "memory");    // keep ds_writes ordered before ds_reads
        bf16x8 pa0 = *(const bf16x8*)&Pw[wv][l15 * PWLDU + quad * 4];
        bf16x8 pa1 = *(const bf16x8*)&Pw[wv][l15 * PWLDU + 16 + quad * 4];
        #pragma unroll
        for (int dblk = 0; dblk < 4; dblk++) {
            o[dblk] = __builtin_amdgcn_mfma_f32_16x16x32_bf16(pa0, vf[dblk][0], o[dblk], 0, 0, 0);
            o[dblk] = __builtin_amdgcn_mfma_f32_16x16x32_bf16(pa1, vf[dblk][1], o[dblk], 0, 0, 0);
        }
    }

    #pragma unroll
    for (int dblk = 0; dblk < 4; dblk++)
        #pragma unroll
        for (int reg = 0; reg < 4; reg++)
            Ob[wv][quad * 4 + reg][16 * dblk + l15] = o[dblk][reg];
    __syncthreads();
    {
        const int s  = tid >> 4;          // 0..31
        const int gg = s >> 4, si = s & 15;
        const int d0 = (tid & 15) * 4;
        f32x4 r0 = *(const f32x4*)&Ob[gg * 4 + 0][si][d0];
        f32x4 r1 = *(const f32x4*)&Ob[gg * 4 + 1][si][d0];
        f32x4 r2 = *(const f32x4*)&Ob[gg * 4 + 2][si][d0];
        f32x4 r3 = *(const f32x4*)&Ob[gg * 4 + 3][si][d0];
        f32x4 r = (r0 + r1) + (r2 + r3);
        *(f32x4*)(Att + ((size_t)(b * S_ + sB + s)) * D_ + d0) = r;
    }
}

// ---------------------------------------------------------------------------
extern "C" void kernel_launch(void* const* d_in, const int* in_sizes, int n_in,
                              void* d_out, int out_size, void* d_ws, size_t ws_size,
                              hipStream_t stream)
{
    const float* q  = (const float*)d_in[0];
    const float* k  = (const float*)d_in[1];
    const float* v  = (const float*)d_in[2];
    const unsigned char* mask = (const unsigned char*)d_in[3];
    const float* wq = (const float*)d_in[4];
    const float* wk = (const float*)d_in[5];
    const float* wv = (const float*)d_in[6];

    float* out = (float*)d_out;
    float* Att = out;                                  // [B,S,D]
    float* Sc  = out + (size_t)B_ * S_ * D_;           // [B,S,S]

    // ws: Wb (384 KB) | Qb (2MB) | Kb (2MB) | VT (2MB) | Inv (64 KB)
    unsigned short* Wb = (unsigned short*)d_ws;
    unsigned short* Qb = Wb + (size_t)3 * 65536;
    unsigned short* Kb = Qb + (size_t)B_ * S_ * D_;
    unsigned short* VT = Kb + (size_t)B_ * S_ * D_;
    float* Invw = (float*)(VT + (size_t)B_ * S_ * D_);

    hipLaunchKernelGGL(wconv_kernel, dim3(192), dim3(256), 0, stream, wq, wk, wv, Wb);
    hipLaunchKernelGGL(proj_kernel, dim3(256, 3), dim3(256), 0, stream,
                       q, k, v, Wb, Qb, Kb, VT);
    hipLaunchKernelGGL(sum_kernel, dim3(512), dim3(512), 0, stream,
                       Qb, Kb, mask, Invw);
    hipLaunchKernelGGL(emit_kernel, dim3(512), dim3(512), 0, stream,
                       Qb, Kb, VT, mask, Invw, Sc, Att);
}